// Round 9
// baseline (1175.204 us; speedup 1.0000x reference)
//
// AttLayer block-local attention, MI355X gfx950.
// R9: B operand direct global->VGPR (no LDS staging for B). Three schedule
//     variants all plateaued at 37-38% -> binding resource is shared LDS
//     traffic (192KB reads + 64KB writes per K-tile ~ 1500+cyc vs 621 MFMA).
//     Now: LDS holds A only (2x32KB dbuf); B fragments load straight from
//     global (16 rows x 64B contiguous per wave-read, L1/L2-served, 2-wave
//     reuse), double-buffered in regs fbE/fbO (static names). 2 barriers and
//     ONE manual VM(12) per K-tile (certifies prev tile's A-stage; derived
//     from issue stream [fa_ds16 | fbN_vm8 | LGKM0 | SBAR | stageA_vm4 |
//     MFMA | VM(12) | SBAR], consistent for prologue/steady state). B RAW
//     waits are compiler-tracked counted vmcnt. Guards for S/PV per-lane on
//     the B load. VGPR ~200-230 within (512,2) cap 256 - watch WRITE_SIZE.
// Workspace: xT | Wqk | Wv | Wo | qkT | v | S | P | guard (attT aliases xT).

#include <hip/hip_runtime.h>
#include <hip/hip_bf16.h>

typedef __attribute__((ext_vector_type(4))) float f32x4;
typedef __attribute__((ext_vector_type(8))) __bf16 bf16x8;

struct ushort4_t { unsigned short x, y, z, w; };

#define DEVINL static __device__ __forceinline__

DEVINL unsigned short f2bf(float f) {  // RTNE float->bf16
  union { float f; unsigned u; } x; x.f = f;
  return (unsigned short)((x.u + 0x7FFFu + ((x.u >> 16) & 1u)) >> 16);
}

DEVINL void gload16(const void* g, void* l) {
  __builtin_amdgcn_global_load_lds((const __attribute__((address_space(1))) void*)g,
                                   (__attribute__((address_space(3))) void*)l,
                                   16, 0, 0);
}

#define SBAR()   asm volatile("s_barrier" ::: "memory")
#define LGKM0()  asm volatile("s_waitcnt lgkmcnt(0)" ::: "memory")
#define VM(n)    asm volatile("s_waitcnt vmcnt(" #n ")" ::: "memory")
#define SCHED0() __builtin_amdgcn_sched_barrier(0)

// ---------------------------------------------------------------- transpose x
__global__ __launch_bounds__(256) void transpose_x_k(const float* __restrict__ x,
                                                     unsigned short* __restrict__ xT) {
  __shared__ float tile[32][33];
  const int bx = blockIdx.x;  // 512
  const int by = blockIdx.y;  // 64
  const int tx = threadIdx.x; // 32
  const int ty = threadIdx.y; // 8
#pragma unroll
  for (int i = 0; i < 4; ++i) {
    int c = by * 32 + ty + i * 8;
    tile[ty + i * 8][tx] = x[(long)c * 16384 + bx * 32 + tx];
  }
  __syncthreads();
  const int t = ty * 32 + tx;
  const int lrow = t >> 3;
  const int cq = (t & 7) << 2;
  ushort4_t o;
  o.x = f2bf(tile[cq + 0][lrow]);
  o.y = f2bf(tile[cq + 1][lrow]);
  o.z = f2bf(tile[cq + 2][lrow]);
  o.w = f2bf(tile[cq + 3][lrow]);
  *reinterpret_cast<ushort4_t*>(xT + (long)(bx * 32 + lrow) * 2048 + by * 32 + cq) = o;
}

// ------------------------------------------------------------ weight convert
__global__ __launch_bounds__(256) void conv_w_k(const float* __restrict__ wq,
                                                const float* __restrict__ wk,
                                                const float* __restrict__ wv,
                                                const float* __restrict__ wo,
                                                unsigned short* __restrict__ Wqk,
                                                unsigned short* __restrict__ Wv,
                                                unsigned short* __restrict__ Wo) {
  long i = ((long)blockIdx.x * 256 + threadIdx.x) * 4;   // 0..8388604
  const float* src;
  unsigned short* dst;
  if (i < 4194304) {
    src = (i < 2097152) ? (wq + i) : (wk + i - 2097152);
    dst = Wqk + i;
  } else if (i < 6291456) {
    src = wv + (i - 4194304);
    dst = Wv + (i - 4194304);
  } else {
    src = wo + (i - 6291456);
    dst = Wo + (i - 6291456);
  }
  float4 v = *reinterpret_cast<const float4*>(src);
  ushort4_t o{f2bf(v.x), f2bf(v.y), f2bf(v.z), f2bf(v.w)};
  *reinterpret_cast<ushort4_t*>(dst) = o;
}

// ------------------------------------------------------------------ GEMM core
enum { EPI_QK = 0, EPI_V = 1, EPI_S = 2, EPI_PV = 3, EPI_OUT = 4 };

struct GArgs {
  const unsigned short* A;
  const unsigned short* Bt;
  void* C;
  const float* bias;
  const float* bias2;
  const float* mask;
  const unsigned short* guard;
  int aBatch, cBatch;
  int btRow0, btRow0Step, btRowLim;
  int btK0, btK0Step, btKLim;
};

// 256x256 tile, BK=64, 8 waves (2M x 4N), per-wave 128x64. A via LDS dbuf,
// B direct global->VGPR dbuf.
template <int EPI, int GUARDED, int LDA, int LDB, int LDC, int KK>
__global__ __launch_bounds__(512, 2) void gemmD_k(GArgs g) {
  constexpr int NK = KK >> 6;   // K-tiles of 64
  __shared__ char lds[65536];   // A only: 2 buffers x 32KB

  const int t = threadIdx.x;
  const int l = t & 63;
  const int w = t >> 6;

  // XCD chunk swizzle (all grids % 8 == 0).
  const int gx = gridDim.x, gxy = gx * gridDim.y;
  const int nwg = gxy * gridDim.z;
  int lin = blockIdx.z * gxy + blockIdx.y * gx + blockIdx.x;
  lin = (lin & 7) * (nwg >> 3) + (lin >> 3);
  const int z = lin / gxy;
  const int rres = lin - z * gxy;
  const int Mbase = (rres / gx) << 8;
  const int Nbase = (rres - (rres / gx) * gx) << 8;

  const int wr = w >> 2;
  const int wc = w & 3;
  const int fr = l & 15;
  const int fg = l >> 4;

  const unsigned short* Ab = g.A + (long)z * g.aBatch + (long)Mbase * LDA;
  const int bRowBase = g.btRow0 + z * g.btRow0Step + Nbase;
  const int bK0 = g.btK0 + z * g.btK0Step;

  const int rr = t >> 3;
  const int cb8s = t & 7;

  // stage one 16KB A-half (rows half*64 + {0..63} and +128) of K-tile kt.
  auto stageA = [&](int bufSel, int half, int kt) {
    const int k0 = (kt & (NK - 1)) << 6;
#pragma unroll
    for (int gph = 0; gph < 2; ++gph) {
      const int row = (half << 6) + (gph << 7) + rr;
      const int cbL = cb8s ^ (row & 7);
      const int gk = k0 + (cbL << 3);
      char* lp = lds + (bufSel << 15) + row * 128 + (cb8s << 4);
      gload16((const char*)(Ab + (long)row * LDA + gk), lp);
    }
  };

  const int arow = (wr << 7) + fr;
  const int brow = (wc << 6) + fr;

  auto ldA = [&](int i8, int kk, int bufSel) -> bf16x8 {
    const int row = arow + (i8 << 4);
    const int cb = ((kk << 2) | fg) ^ (row & 7);
    return *(const bf16x8*)(lds + (bufSel << 15) + row * 128 + (cb << 4));
  };

  // B fragment direct from global: 16B per lane, 16 rows x 64B contiguous.
  auto ldBg = [&](int j, int kk, int kt) -> bf16x8 {
    const int k0 = (kt & (NK - 1)) << 6;
    const int gr = bRowBase + brow + (j << 4);
    const int gc = bK0 + k0 + (kk << 5) + (fg << 3);
    const unsigned short* ptr;
    if (!GUARDED ||
        ((unsigned)gr < (unsigned)g.btRowLim && (unsigned)gc < (unsigned)g.btKLim))
      ptr = g.Bt + (long)gr * LDB + gc;
    else
      ptr = g.guard + ((l & 31) << 3);
    return *(const bf16x8*)ptr;
  };

  f32x4 acc[8][4];
#pragma unroll
  for (int i = 0; i < 8; ++i)
#pragma unroll
    for (int j = 0; j < 4; ++j) acc[i][j] = f32x4{0.f, 0.f, 0.f, 0.f};

  bf16x8 fa[8][2], fbE[4][2], fbO[4][2];

// 32 MFMA: rows I0..I0+3 x all 4 B fragments, kk-outer.
#define MQ2(I0, FB)                                                           \
  __builtin_amdgcn_s_setprio(1);                                              \
  _Pragma("unroll") for (int kk = 0; kk < 2; ++kk)                            \
  _Pragma("unroll") for (int i = 0; i < 4; ++i)                               \
  _Pragma("unroll") for (int j = 0; j < 4; ++j)                               \
    acc[(I0) + i][j] = __builtin_amdgcn_mfma_f32_16x16x32_bf16(               \
        fa[(I0) + i][kk], FB[j][kk], acc[(I0) + i][j], 0, 0, 0);              \
  __builtin_amdgcn_s_setprio(0);

// One K-tile. Issue stream: fa_ds(16) | fbN_vm(8) | MQ2(0) | LGKM0 | SBAR |
// stageA_vm(4) | MQ2(4) | VM(12) | SBAR.  VM(12) leaves {prev-half? no:}
// exactly {fbN(8) + this stageA(4)} outstanding -> drains prev tile's
// A-stage (4) => next tile's LDS buffer certified. fbCur RAW handled by
// compiler-counted vmcnt (reg deps).
#define TILE(CUR, FBC, FBN, KT)                                               \
  {                                                                           \
    _Pragma("unroll") for (int i = 0; i < 8; ++i) {                           \
      fa[i][0] = ldA(i, 0, CUR); fa[i][1] = ldA(i, 1, CUR); }                 \
    _Pragma("unroll") for (int j = 0; j < 4; ++j) {                           \
      FBN[j][0] = ldBg(j, 0, (KT) + 1); FBN[j][1] = ldBg(j, 1, (KT) + 1); }   \
    MQ2(0, FBC);                                                              \
    LGKM0(); SCHED0();                                                        \
    SBAR();                                                                   \
    stageA(CUR, 0, (KT) + 2); stageA(CUR, 1, (KT) + 2);                       \
    MQ2(4, FBC);                                                              \
    VM(12); SCHED0(); SBAR();                                                 \
  }

  // prologue: A(0)->buf0, A(1)->buf1 (8 gloads), fbE = B(0) (8 loads).
  stageA(0, 0, 0); stageA(0, 1, 0);
  stageA(1, 0, 1); stageA(1, 1, 1);
  SCHED0();
#pragma unroll
  for (int j = 0; j < 4; ++j) { fbE[j][0] = ldBg(j, 0, 0); fbE[j][1] = ldBg(j, 1, 0); }
  SCHED0();
  VM(12);       // drain A(0): outstanding = A(1)(4) + fbE(8)
  SBAR();

#pragma unroll 1
  for (int it = 0; it < NK / 2; ++it) {
    TILE(0, fbE, fbO, 2 * it);
    TILE(1, fbO, fbE, 2 * it + 1);
  }
  VM(0); LGKM0(); SBAR();  // drain wrapped prefetches before epilogue

  // epilogue: D row=(lane>>4)*4+r, col=lane&15 within each 16x16 fragment
#pragma unroll
  for (int ii = 0; ii < 8; ++ii)
#pragma unroll
    for (int j = 0; j < 4; ++j)
#pragma unroll
      for (int r = 0; r < 4; ++r) {
        const int row = Mbase + (wr << 7) + ii * 16 + fg * 4 + r;
        const int col = Nbase + (wc << 6) + j * 16 + fr;
        float val = acc[ii][j][r];
        const long off = (long)z * g.cBatch + (long)row * LDC + col;
        if (EPI == EPI_QK) {
          val = (col < 1024) ? (val + g.bias[col]) * 0.03125f
                             : (val + g.bias2[col - 1024]);
          ((unsigned short*)g.C)[off] = f2bf(val);
        } else if (EPI == EPI_V) {
          val += g.bias[row];
          ((unsigned short*)g.C)[off] = f2bf(val);
        } else if (EPI == EPI_S) {
          ((float*)g.C)[off] = val;
        } else if (EPI == EPI_PV) {
          val = fmaxf(val, 0.f);
          ((unsigned short*)g.C)[off] = f2bf(val);
        } else {
          val = (val + g.bias[row]) * g.mask[col];
          ((float*)g.C)[off] = val;
        }
      }
#undef TILE
#undef MQ2
}

// ------------------------------------------------------------------- softmax
__global__ __launch_bounds__(256) void softmax_k(const float* __restrict__ S,
                                                 const float* __restrict__ mask,
                                                 unsigned short* __restrict__ P) {
  const int row = blockIdx.x;      // n*512 + l
  const int n = row >> 9;
  const float* s = S + (long)row * 1024;
  unsigned short* p = P + (long)row * 1024;
  const int t = threadIdx.x;

  const float4 sv = *reinterpret_cast<const float4*>(s + t * 4);
  const int pos0 = (n << 9) + t * 4 - 256;
  float4 mv = {0.f, 0.f, 0.f, 0.f};
  if ((unsigned)pos0 < 16384u) mv = *reinterpret_cast<const float4*>(mask + pos0);
  float fm[4] = {mv.x, mv.y, mv.z, mv.w};
  if (t == 255) fm[3] = 0.f;       // m == 1023 excluded by window mask
  const float sc[4] = {sv.x, sv.y, sv.z, sv.w};

  float logit[4];
  float lmax = -3.0e38f;
#pragma unroll
  for (int k = 0; k < 4; ++k) {
    logit[k] = sc[k] + logf(fm[k] + 1e-9f);
    lmax = fmaxf(lmax, logit[k]);
  }
#pragma unroll
  for (int o = 32; o; o >>= 1) lmax = fmaxf(lmax, __shfl_xor(lmax, o, 64));
  __shared__ float red[8];
  const int wv_ = t >> 6, ln = t & 63;
  if (ln == 0) red[wv_] = lmax;
  __syncthreads();
  const float gmax = fmaxf(fmaxf(red[0], red[1]), fmaxf(red[2], red[3]));

  float e[4], lsum = 0.f;
#pragma unroll
  for (int k = 0; k < 4; ++k) { e[k] = expf(logit[k] - gmax); lsum += e[k]; }
#pragma unroll
  for (int o = 32; o; o >>= 1) lsum += __shfl_xor(lsum, o, 64);
  if (ln == 0) red[4 + wv_] = lsum;
  __syncthreads();
  const float inv = 1.f / ((red[4] + red[5]) + (red[6] + red[7]));
  ushort4_t o4;
  o4.x = f2bf(e[0] * inv * fm[0]);
  o4.y = f2bf(e[1] * inv * fm[1]);
  o4.z = f2bf(e[2] * inv * fm[2]);
  o4.w = f2bf(e[3] * inv * fm[3]);
  *reinterpret_cast<ushort4_t*>(p + t * 4) = o4;
}

// -------------------------------------------------------------------- launch
extern "C" void kernel_launch(void* const* d_in, const int* in_sizes, int n_in,
                              void* d_out, int out_size, void* d_ws, size_t ws_size,
                              hipStream_t stream) {
  const float* x1 = (const float*)d_in[0];
  const float* mask = (const float*)d_in[2];
  const float* wq = (const float*)d_in[3];
  const float* bq = (const float*)d_in[4];
  const float* wk = (const float*)d_in[5];
  const float* bk = (const float*)d_in[6];
  const float* wv = (const float*)d_in[7];
  const float* bv = (const float*)d_in[8];
  const float* wo = (const float*)d_in[9];
  const float* bo = (const float*)d_in[10];

  char* ws = (char*)d_ws;
  unsigned short* xT   = (unsigned short*)(ws);
  unsigned short* attT = xT;                                     // alias
  unsigned short* Wqk  = (unsigned short*)(ws + 67108864);
  unsigned short* Wv   = (unsigned short*)(ws + 75497472);
  unsigned short* Wo   = (unsigned short*)(ws + 79691776);
  unsigned short* qkT  = (unsigned short*)(ws + 83886080);
  unsigned short* vbuf = (unsigned short*)(ws + 150994944);
  float*          Sbuf = (float*)(ws + 184549376);
  unsigned short* P    = (unsigned short*)(ws + 251658240);
  unsigned short* guard= (unsigned short*)(ws + 285212672);

  hipMemsetAsync(guard, 0, 4096, stream);

  transpose_x_k<<<dim3(512, 64), dim3(32, 8), 0, stream>>>(x1, xT);
  conv_w_k<<<dim3(8192), dim3(256), 0, stream>>>(wq, wk, wv, wo, Wqk, Wv, Wo);

  const int BIG = 0x40000000;
  // 1) qkT[16384][2048] = xT @ Wqk^T (+bias, q-part scaled 1/32)
  {
    GArgs a{};
    a.A = xT; a.Bt = Wqk; a.C = qkT;
    a.bias = bq; a.bias2 = bk; a.guard = guard;
    a.aBatch = 0; a.cBatch = 0;
    a.btRow0 = 0; a.btRow0Step = 0; a.btRowLim = BIG;
    a.btK0 = 0; a.btK0Step = 0; a.btKLim = BIG;
    gemmD_k<EPI_QK, 0, 2048, 2048, 2048, 2048><<<dim3(8, 64, 1), 512, 0, stream>>>(a);
  }
  // 2) v[1024][16384] = Wv @ x (+bv)
  {
    GArgs a{};
    a.A = Wv; a.Bt = xT; a.C = vbuf;
    a.bias = bv; a.guard = guard;
    a.aBatch = 0; a.cBatch = 0;
    a.btRow0 = 0; a.btRow0Step = 0; a.btRowLim = BIG;
    a.btK0 = 0; a.btK0Step = 0; a.btKLim = BIG;
    gemmD_k<EPI_V, 0, 2048, 2048, 16384, 2048><<<dim3(64, 4, 1), 512, 0, stream>>>(a);
  }
  // 3) S[n][512][1024] = Qb @ Kb^T (halo rows via per-lane guard)
  {
    GArgs a{};
    a.A = qkT; a.Bt = qkT; a.C = Sbuf;
    a.guard = guard;
    a.aBatch = 512 * 2048; a.cBatch = 512 * 1024;
    a.btRow0 = -256; a.btRow0Step = 512; a.btRowLim = 16384;
    a.btK0 = 1024; a.btK0Step = 0; a.btKLim = BIG;
    gemmD_k<EPI_S, 1, 2048, 2048, 1024, 1024><<<dim3(4, 2, 32), 512, 0, stream>>>(a);
  }
  // 4) softmax rows -> P bf16
  softmax_k<<<dim3(16384), dim3(256), 0, stream>>>(Sbuf, mask, P);
  // 5) attT[n][512][1024] = relu(P @ Vb^T) (halo cols via per-lane guard)
  {
    GArgs a{};
    a.A = P; a.Bt = vbuf; a.C = attT;
    a.guard = guard;
    a.aBatch = 512 * 1024; a.cBatch = 512 * 1024;
    a.btRow0 = 0; a.btRow0Step = 0; a.btRowLim = BIG;
    a.btK0 = -256; a.btK0Step = 512; a.btKLim = 16384;
    gemmD_k<EPI_PV, 1, 1024, 16384, 1024, 1024><<<dim3(4, 2, 32), 512, 0, stream>>>(a);
  }
  // 6) out[2048][16384] = (Wo @ attT^T + bo) * mask (fp32)
  {
    GArgs a{};
    a.A = Wo; a.Bt = attT; a.C = d_out;
    a.bias = bo; a.mask = mask; a.guard = guard;
    a.aBatch = 0; a.cBatch = 0;
    a.btRow0 = 0; a.btRow0Step = 0; a.btRowLim = BIG;
    a.btK0 = 0; a.btK0Step = 0; a.btKLim = BIG;
    gemmD_k<EPI_OUT, 0, 1024, 1024, 16384, 1024><<<dim3(64, 8, 1), 512, 0, stream>>>(a);
  }
  (void)in_sizes; (void)n_in; (void)out_size; (void)ws_size;
}

// Round 10
// 459.017 us; speedup vs baseline: 2.5603x; 2.5603x over previous
//
// AttLayer block-local attention, MI355X gfx950.
// R10: R6 schedule (best verified: 464us) + addressing hoisted to base regs.
//   - LDS remap: A @ buf*32768, B @ 65536+buf*32768 so every ds_read is
//     base_kk + LITERAL (folds into ds_read offset field; HK technique #8).
//     4 read-base VGPRs (aRd0/aRd1/bRd0/bRd1), ~0 VALU per fragment read.
//   - stage(): per-thread global+LDS bases; row term compile-time, k0b shared.
//     Guarded-B (S/PV) keeps full-math path; A always fast.
//   R9 lesson recorded: B-direct-to-VGPR spills (WRITE 768MB) and triples
//   FETCH (loses B-panel reuse) -> B stays through LDS.
// Sync structure byte-identical to R6 (VM(6)@P3/P7, SBAR/LGKM0, setprio).
// Workspace: xT | Wqk | Wv | Wo | qkT | v | S | P | guard (attT aliases xT).

#include <hip/hip_runtime.h>
#include <hip/hip_bf16.h>

typedef __attribute__((ext_vector_type(4))) float f32x4;
typedef __attribute__((ext_vector_type(8))) __bf16 bf16x8;

struct ushort4_t { unsigned short x, y, z, w; };

#define DEVINL static __device__ __forceinline__

DEVINL unsigned short f2bf(float f) {  // RTNE float->bf16
  union { float f; unsigned u; } x; x.f = f;
  return (unsigned short)((x.u + 0x7FFFu + ((x.u >> 16) & 1u)) >> 16);
}

DEVINL void gload16(const void* g, void* l) {
  __builtin_amdgcn_global_load_lds((const __attribute__((address_space(1))) void*)g,
                                   (__attribute__((address_space(3))) void*)l,
                                   16, 0, 0);
}

#define SBAR()   asm volatile("s_barrier" ::: "memory")
#define LGKM0()  asm volatile("s_waitcnt lgkmcnt(0)" ::: "memory")
#define LGKM8()  asm volatile("s_waitcnt lgkmcnt(8)" ::: "memory")
#define VM(n)    asm volatile("s_waitcnt vmcnt(" #n ")" ::: "memory")

// ---------------------------------------------------------------- transpose x
__global__ __launch_bounds__(256) void transpose_x_k(const float* __restrict__ x,
                                                     unsigned short* __restrict__ xT) {
  __shared__ float tile[32][33];
  const int bx = blockIdx.x;  // 512
  const int by = blockIdx.y;  // 64
  const int tx = threadIdx.x; // 32
  const int ty = threadIdx.y; // 8
#pragma unroll
  for (int i = 0; i < 4; ++i) {
    int c = by * 32 + ty + i * 8;
    tile[ty + i * 8][tx] = x[(long)c * 16384 + bx * 32 + tx];
  }
  __syncthreads();
  const int t = ty * 32 + tx;
  const int lrow = t >> 3;
  const int cq = (t & 7) << 2;
  ushort4_t o;
  o.x = f2bf(tile[cq + 0][lrow]);
  o.y = f2bf(tile[cq + 1][lrow]);
  o.z = f2bf(tile[cq + 2][lrow]);
  o.w = f2bf(tile[cq + 3][lrow]);
  *reinterpret_cast<ushort4_t*>(xT + (long)(bx * 32 + lrow) * 2048 + by * 32 + cq) = o;
}

// ------------------------------------------------------------ weight convert
__global__ __launch_bounds__(256) void conv_w_k(const float* __restrict__ wq,
                                                const float* __restrict__ wk,
                                                const float* __restrict__ wv,
                                                const float* __restrict__ wo,
                                                unsigned short* __restrict__ Wqk,
                                                unsigned short* __restrict__ Wv,
                                                unsigned short* __restrict__ Wo) {
  long i = ((long)blockIdx.x * 256 + threadIdx.x) * 4;   // 0..8388604
  const float* src;
  unsigned short* dst;
  if (i < 4194304) {
    src = (i < 2097152) ? (wq + i) : (wk + i - 2097152);
    dst = Wqk + i;
  } else if (i < 6291456) {
    src = wv + (i - 4194304);
    dst = Wv + (i - 4194304);
  } else {
    src = wo + (i - 6291456);
    dst = Wo + (i - 6291456);
  }
  float4 v = *reinterpret_cast<const float4*>(src);
  ushort4_t o{f2bf(v.x), f2bf(v.y), f2bf(v.z), f2bf(v.w)};
  *reinterpret_cast<ushort4_t*>(dst) = o;
}

// ------------------------------------------------------------------ GEMM core
enum { EPI_QK = 0, EPI_V = 1, EPI_S = 2, EPI_PV = 3, EPI_OUT = 4 };

struct GArgs {
  const unsigned short* A;
  const unsigned short* Bt;
  void* C;
  const float* bias;
  const float* bias2;
  const float* mask;
  const unsigned short* guard;
  int aBatch, cBatch;
  int btRow0, btRow0Step, btRowLim;
  int btK0, btK0Step, btKLim;
};

// 256x256 tile, BK=64, 8 waves (2M x 4N), per-wave 128x64, 8-phase pipeline.
// LDS: A @ buf*32768, B @ 65536 + buf*32768.
template <int EPI, int GUARDED, int LDA, int LDB, int LDC, int KK>
__global__ __launch_bounds__(512, 2) void gemm8_k(GArgs g) {
  constexpr int NK = KK >> 6;
  constexpr int NT = NK >> 1;
  __shared__ char lds[131072];

  const int t = threadIdx.x;
  const int l = t & 63;
  const int w = t >> 6;

  // XCD chunk swizzle (all grids % 8 == 0).
  const int gx = gridDim.x, gxy = gx * gridDim.y;
  const int nwg = gxy * gridDim.z;
  int lin = blockIdx.z * gxy + blockIdx.y * gx + blockIdx.x;
  lin = (lin & 7) * (nwg >> 3) + (lin >> 3);
  const int z = lin / gxy;
  const int rres = lin - z * gxy;
  const int Mbase = (rres / gx) << 8;
  const int Nbase = (rres - (rres / gx) * gx) << 8;

  const int wr = w >> 2;
  const int wc = w & 3;
  const int fr = l & 15;
  const int fg = l >> 4;

  const unsigned short* Ab = g.A + (long)z * g.aBatch + (long)Mbase * LDA;
  const int bRowBase = g.btRow0 + z * g.btRow0Step + Nbase;
  const int bK0 = g.btK0 + z * g.btK0Step;

  // ---- staging bases (per-thread, loop-invariant) ----
  const int rr = t >> 3;                       // A staging row-within-chunk
  const int cb8s = t & 7;                      // staging 16B slot
  const int cbL = cb8s ^ (rr & 7);             // pre-swizzled source slot
  const int bRowT = (rr & 31) + ((rr >> 5) << 6);  // B staging row-within-chunk
  const char* aStageG = (const char*)(Ab + (long)rr * LDA) + (cbL << 4);
  const char* bStageG = (const char*)(g.Bt + (long)(bRowBase + bRowT) * LDB + bK0) + (cbL << 4);
  char* aStageL = lds + rr * 128 + (cb8s << 4);
  char* bStageL = lds + 65536 + bRowT * 128 + (cb8s << 4);

  // stage one 16 KiB unit (2 gloads/thread) of K-tile kt into buf.
  // unit 0: A rows 0-63,128-191   unit 3: A rows 64-127,192-255
  // unit 1: B rows {0-31,64-95},{128-159,192-223}
  // unit 2: B rows {32-63,96-127},{160-191,224-255}
  auto stage = [&](int bufSel, int unit, int kt) {
    const int k0b = (kt & (NK - 1)) << 7;      // byte offset along K
    const bool isA = (unit == 0) || (unit == 3);
#pragma unroll
    for (int gph = 0; gph < 2; ++gph) {
      const int rowAdd = (isA ? (unit == 0 ? 0 : 64) : (unit == 1 ? 0 : 32)) + (gph << 7);
      if (isA) {
        gload16(aStageG + (long)rowAdd * (LDA * 2) + k0b,
                aStageL + bufSel * 32768 + rowAdd * 128);
      } else if (!GUARDED) {
        gload16(bStageG + (long)rowAdd * (LDB * 2) + k0b,
                bStageL + bufSel * 32768 + rowAdd * 128);
      } else {
        const int row = rowAdd + bRowT;
        const int gk = ((kt & (NK - 1)) << 6) + (cbL << 3);
        const int grow = bRowBase + row;
        const int gkk = bK0 + gk;
        const char* gp =
            ((unsigned)grow < (unsigned)g.btRowLim && (unsigned)gkk < (unsigned)g.btKLim)
                ? (const char*)(g.Bt + (long)grow * LDB + gkk)
                : (const char*)g.guard + (l << 4);
        gload16(gp, bStageL + bufSel * 32768 + rowAdd * 128);
      }
    }
  };

  // ---- fragment-read bases: read = base_kk + (BUF*32768 + idx*2048) ----
  const int arow = (wr << 7) + fr;
  const int brow = (wc << 6) + fr;
  const int sA = arow & 7, sB = brow & 7;
  const char* aRd0 = lds + arow * 128 + ((fg ^ sA) << 4);
  const char* aRd1 = lds + arow * 128 + (((4 | fg) ^ sA) << 4);
  const char* bRd0 = lds + 65536 + brow * 128 + ((fg ^ sB) << 4);
  const char* bRd1 = lds + 65536 + brow * 128 + (((4 | fg) ^ sB) << 4);

  f32x4 acc[8][4];
#pragma unroll
  for (int i = 0; i < 8; ++i)
#pragma unroll
    for (int j = 0; j < 4; ++j) acc[i][j] = f32x4{0.f, 0.f, 0.f, 0.f};

  // prologue: buf0 fully (kt0), buf1 units 0-2 (kt1). 14 gloads in flight.
  stage(0, 0, 0); stage(0, 1, 0); stage(0, 2, 0); stage(0, 3, 0);
  stage(1, 0, 1); stage(1, 1, 1); stage(1, 2, 1);
  VM(6);        // oldest 8 (all of buf0) landed; buf1's 6 stay in flight
  SBAR();

  bf16x8 fa[4][2], fb[4][2];

// fragment reads: literal offsets (fold into ds_read offset field)
#define RA(slot, i8, B) \
  { fa[slot][0] = *(const bf16x8*)(aRd0 + ((B)*32768 + (i8)*2048)); \
    fa[slot][1] = *(const bf16x8*)(aRd1 + ((B)*32768 + (i8)*2048)); }
#define RB(j, B) \
  { fb[j][0] = *(const bf16x8*)(bRd0 + ((B)*32768 + (j)*2048)); \
    fb[j][1] = *(const bf16x8*)(bRd1 + ((B)*32768 + (j)*2048)); }

// kk-outer: dependent MFMAs on the same acc are spaced 8 apart.
#define MFMA_Q(QI, QJ)                                                        \
  __builtin_amdgcn_s_setprio(1);                                              \
  _Pragma("unroll") for (int kk = 0; kk < 2; ++kk)                            \
  _Pragma("unroll") for (int i = 0; i < 4; ++i)                               \
  _Pragma("unroll") for (int j = 0; j < 2; ++j)                               \
    acc[(QI)*4 + i][(QJ)*2 + j] = __builtin_amdgcn_mfma_f32_16x16x32_bf16(    \
        fa[i][kk], fb[(QJ)*2 + j][kk], acc[(QI)*4 + i][(QJ)*2 + j], 0, 0, 0); \
  __builtin_amdgcn_s_setprio(0);

#pragma unroll 1
  for (int it = 0; it < NT; ++it) {
    const int kt1 = 2 * it + 1;
    const int ktn0 = 2 * it + 2;
    const int ktn1 = 2 * it + 3;
    // ---- phase 0 (buf0, Q00) — 12 reads: lgkm(8) pacing hint
    RA(0, 0, 0) RA(1, 1, 0) RA(2, 2, 0) RA(3, 3, 0)
    RB(0, 0) RB(1, 0)
    stage(1, 3, kt1);
    LGKM8();
    SBAR(); LGKM0();
    MFMA_Q(0, 0);
    SBAR();
    // ---- phase 1 (buf0, Q01)
    RB(2, 0) RB(3, 0)
    stage(0, 0, ktn0);
    SBAR(); LGKM0();
    MFMA_Q(0, 1);
    SBAR();
    // ---- phase 2 (buf0, Q10)
    RA(0, 4, 0) RA(1, 5, 0) RA(2, 6, 0) RA(3, 7, 0)
    stage(0, 1, ktn0);
    SBAR(); LGKM0();
    MFMA_Q(1, 0);
    SBAR();
    // ---- phase 3 (buf0, Q11)
    stage(0, 2, ktn0);
    SBAR(); LGKM0();
    MFMA_Q(1, 1);
    VM(6);       // buf1 (kt1) fully landed before phase 4
    SBAR();
    // ---- phase 4 (buf1, Q00) — 12 reads: lgkm(8) pacing hint
    RA(0, 0, 1) RA(1, 1, 1) RA(2, 2, 1) RA(3, 3, 1)
    RB(0, 1) RB(1, 1)
    stage(0, 3, ktn0);
    LGKM8();
    SBAR(); LGKM0();
    MFMA_Q(0, 0);
    SBAR();
    // ---- phase 5 (buf1, Q01)
    RB(2, 1) RB(3, 1)
    stage(1, 0, ktn1);
    SBAR(); LGKM0();
    MFMA_Q(0, 1);
    SBAR();
    // ---- phase 6 (buf1, Q10)
    RA(0, 4, 1) RA(1, 5, 1) RA(2, 6, 1) RA(3, 7, 1)
    stage(1, 1, ktn1);
    SBAR(); LGKM0();
    MFMA_Q(1, 0);
    SBAR();
    // ---- phase 7 (buf1, Q11)
    stage(1, 2, ktn1);
    SBAR(); LGKM0();
    MFMA_Q(1, 1);
    VM(6);       // buf0 (ktn0) fully landed before next phase 0
    SBAR();
  }
  VM(0); LGKM0(); SBAR();  // drain wrapped prefetches before epilogue

  // epilogue: D row=(lane>>4)*4+r, col=lane&15 within each 16x16 fragment
#pragma unroll
  for (int ii = 0; ii < 8; ++ii)
#pragma unroll
    for (int j = 0; j < 4; ++j)
#pragma unroll
      for (int r = 0; r < 4; ++r) {
        const int row = Mbase + (wr << 7) + ii * 16 + fg * 4 + r;
        const int col = Nbase + (wc << 6) + j * 16 + fr;
        float val = acc[ii][j][r];
        const long off = (long)z * g.cBatch + (long)row * LDC + col;
        if (EPI == EPI_QK) {
          val = (col < 1024) ? (val + g.bias[col]) * 0.03125f
                             : (val + g.bias2[col - 1024]);
          ((unsigned short*)g.C)[off] = f2bf(val);
        } else if (EPI == EPI_V) {
          val += g.bias[row];
          ((unsigned short*)g.C)[off] = f2bf(val);
        } else if (EPI == EPI_S) {
          ((float*)g.C)[off] = val;
        } else if (EPI == EPI_PV) {
          val = fmaxf(val, 0.f);
          ((unsigned short*)g.C)[off] = f2bf(val);
        } else {
          val = (val + g.bias[row]) * g.mask[col];
          ((float*)g.C)[off] = val;
        }
      }
#undef MFMA_Q
#undef RA
#undef RB
}

// ------------------------------------------------------------------- softmax
__global__ __launch_bounds__(256) void softmax_k(const float* __restrict__ S,
                                                 const float* __restrict__ mask,
                                                 unsigned short* __restrict__ P) {
  const int row = blockIdx.x;      // n*512 + l
  const int n = row >> 9;
  const float* s = S + (long)row * 1024;
  unsigned short* p = P + (long)row * 1024;
  const int t = threadIdx.x;

  const float4 sv = *reinterpret_cast<const float4*>(s + t * 4);
  const int pos0 = (n << 9) + t * 4 - 256;
  float4 mv = {0.f, 0.f, 0.f, 0.f};
  if ((unsigned)pos0 < 16384u) mv = *reinterpret_cast<const float4*>(mask + pos0);
  float fm[4] = {mv.x, mv.y, mv.z, mv.w};
  if (t == 255) fm[3] = 0.f;       // m == 1023 excluded by window mask
  const float sc[4] = {sv.x, sv.y, sv.z, sv.w};

  float logit[4];
  float lmax = -3.0e38f;
#pragma unroll
  for (int k = 0; k < 4; ++k) {
    logit[k] = sc[k] + logf(fm[k] + 1e-9f);
    lmax = fmaxf(lmax, logit[k]);
  }
#pragma unroll
  for (int o = 32; o; o >>= 1) lmax = fmaxf(lmax, __shfl_xor(lmax, o, 64));
  __shared__ float red[8];
  const int wv_ = t >> 6, ln = t & 63;
  if (ln == 0) red[wv_] = lmax;
  __syncthreads();
  const float gmax = fmaxf(fmaxf(red[0], red[1]), fmaxf(red[2], red[3]));

  float e[4], lsum = 0.f;
#pragma unroll
  for (int k = 0; k < 4; ++k) { e[k] = expf(logit[k] - gmax); lsum += e[k]; }
#pragma unroll
  for (int o = 32; o; o >>= 1) lsum += __shfl_xor(lsum, o, 64);
  if (ln == 0) red[4 + wv_] = lsum;
  __syncthreads();
  const float inv = 1.f / ((red[4] + red[5]) + (red[6] + red[7]));
  ushort4_t o4;
  o4.x = f2bf(e[0] * inv * fm[0]);
  o4.y = f2bf(e[1] * inv * fm[1]);
  o4.z = f2bf(e[2] * inv * fm[2]);
  o4.w = f2bf(e[3] * inv * fm[3]);
  *reinterpret_cast<ushort4_t*>(p + t * 4) = o4;
}

// -------------------------------------------------------------------- launch
extern "C" void kernel_launch(void* const* d_in, const int* in_sizes, int n_in,
                              void* d_out, int out_size, void* d_ws, size_t ws_size,
                              hipStream_t stream) {
  const float* x1 = (const float*)d_in[0];
  const float* mask = (const float*)d_in[2];
  const float* wq = (const float*)d_in[3];
  const float* bq = (const float*)d_in[4];
  const float* wk = (const float*)d_in[5];
  const float* bk = (const float*)d_in[6];
  const float* wv = (const float*)d_in[7];
  const float* bv = (const float*)d_in[8];
  const float* wo = (const float*)d_in[9];
  const float* bo = (const float*)d_in[10];

  char* ws = (char*)d_ws;
  unsigned short* xT   = (unsigned short*)(ws);
  unsigned short* attT = xT;                                     // alias
  unsigned short* Wqk  = (unsigned short*)(ws + 67108864);
  unsigned short* Wv   = (unsigned short*)(ws + 75497472);
  unsigned short* Wo   = (unsigned short*)(ws + 79691776);
  unsigned short* qkT  = (unsigned short*)(ws + 83886080);
  unsigned short* vbuf = (unsigned short*)(ws + 150994944);
  float*          Sbuf = (float*)(ws + 184549376);
  unsigned short* P    = (unsigned short*)(ws + 251658240);
  unsigned short* guard= (unsigned short*)(ws + 285212672);

  hipMemsetAsync(guard, 0, 4096, stream);

  transpose_x_k<<<dim3(512, 64), dim3(32, 8), 0, stream>>>(x1, xT);
  conv_w_k<<<dim3(8192), dim3(256), 0, stream>>>(wq, wk, wv, wo, Wqk, Wv, Wo);

  const int BIG = 0x40000000;
  // 1) qkT[16384][2048] = xT @ Wqk^T (+bias, q-part scaled 1/32)
  {
    GArgs a{};
    a.A = xT; a.Bt = Wqk; a.C = qkT;
    a.bias = bq; a.bias2 = bk; a.guard = guard;
    a.aBatch = 0; a.cBatch = 0;
    a.btRow0 = 0; a.btRow0Step = 0; a.btRowLim = BIG;
    a.btK0 = 0; a.btK0Step = 0; a.btKLim = BIG;
    gemm8_k<EPI_QK, 0, 2048, 2048, 2048, 2048><<<dim3(8, 64, 1), 512, 0, stream>>>(a);
  }
  // 2) v[1024][16384] = Wv @ x (+bv)
  {
    GArgs a{};
    a.A = Wv; a.Bt = xT; a.C = vbuf;
    a.bias = bv; a.guard = guard;
    a.aBatch = 0; a.cBatch = 0;
    a.btRow0 = 0; a.btRow0Step = 0; a.btRowLim = BIG;
    a.btK0 = 0; a.btK0Step = 0; a.btKLim = BIG;
    gemm8_k<EPI_V, 0, 2048, 2048, 16384, 2048><<<dim3(64, 4, 1), 512, 0, stream>>>(a);
  }
  // 3) S[n][512][1024] = Qb @ Kb^T (halo rows via guard)
  {
    GArgs a{};
    a.A = qkT; a.Bt = qkT; a.C = Sbuf;
    a.guard = guard;
    a.aBatch = 512 * 2048; a.cBatch = 512 * 1024;
    a.btRow0 = -256; a.btRow0Step = 512; a.btRowLim = 16384;
    a.btK0 = 1024; a.btK0Step = 0; a.btKLim = BIG;
    gemm8_k<EPI_S, 1, 2048, 2048, 1024, 1024><<<dim3(4, 2, 32), 512, 0, stream>>>(a);
  }
  // 4) softmax rows -> P bf16
  softmax_k<<<dim3(16384), dim3(256), 0, stream>>>(Sbuf, mask, P);
  // 5) attT[n][512][1024] = relu(P @ Vb^T) (halo cols via guard)
  {
    GArgs a{};
    a.A = P; a.Bt = vbuf; a.C = attT;
    a.guard = guard;
    a.aBatch = 512 * 1024; a.cBatch = 512 * 1024;
    a.btRow0 = 0; a.btRow0Step = 0; a.btRowLim = BIG;
    a.btK0 = -256; a.btK0Step = 512; a.btKLim = 16384;
    gemm8_k<EPI_PV, 1, 1024, 16384, 1024, 1024><<<dim3(4, 2, 32), 512, 0, stream>>>(a);
  }
  // 6) out[2048][16384] = (Wo @ attT^T + bo) * mask (fp32)
  {
    GArgs a{};
    a.A = Wo; a.Bt = attT; a.C = d_out;
    a.bias = bo; a.mask = mask; a.guard = guard;
    a.aBatch = 0; a.cBatch = 0;
    a.btRow0 = 0; a.btRow0Step = 0; a.btRowLim = BIG;
    a.btK0 = 0; a.btK0Step = 0; a.btKLim = BIG;
    gemm8_k<EPI_OUT, 0, 1024, 1024, 16384, 1024><<<dim3(64, 8, 1), 512, 0, stream>>>(a);
  }
  (void)in_sizes; (void)n_in; (void)out_size; (void)ws_size;
}